// Round 6
// baseline (264.667 us; speedup 1.0000x reference)
//
#include <hip/hip_runtime.h>

// Conditional InstanceNorm2d: x[B=32,C=256,H=64,W=64] fp32, style_id[B] int32,
// gamma/beta[S=16,C=256] fp32 -> out fp32.
//
// Dtype forensics (prior session): all tensors fp32, style_id int32, output
// fp32 (bf16 experiments -> NaN / packed-garbage mismatches).
//
// Session ledger (kernel us = total dur_us - ~157 us harness poison fills):
//   R0 block-lockstep 256thr (LDS reduce):   ~76 | total 233.0
//   R4 wave-per-instance (remat bug):        80.7 | 2.5 TB/s, Occ 42%
//   R5 + asm-pin:                            ~78 | total 234.7
//   R6 persistent dbuf + NT stores:          84.3 | 2.4 TB/s, Occ 17%
//   R7 NT loads + cached stores:             ~72 | total 228.8  <- best
// One-pass plateau: 3.2-3.6 TB/s effective in every structure, while this
// box demonstrably does 6.7 TB/s (harness fill, write-only), 6.29 TB/s
// (float4 copy, m13) and 82-86% BW on LayerNorm/RMSNorm probes. The
// one-pass InstanceNorm couples the streams: each wave drains ALL loads
// before its dependent store burst -> phase-locked read/write bursts.
//
// R8: two-pass via L3, streams decoupled into hardware-proven shapes:
//   Pass A (stats): pure-read streaming reduction; CACHED loads so the
//     128 MiB x lands in the 256 MiB Infinity Cache (doubles as prefetch);
//     lane0 folds (gamma,beta,mean,rstd) -> (scale,shift) into d_ws (64 KB).
//   Pass B (apply): copy-shaped out[i]=fma(x[i],scale,shift); x re-read is
//     L3-hit (NT load: last touch, evict-first, leaves L3 for the write
//     stream); stores normal (R6 showed NT stores regress).
// HBM traffic unchanged (128 cold read + 128 write); predict A ~20us,
// B ~24us, total ~205-212. Mechanism check: pass-B FETCH_SIZE << 128 MiB.

#define HW   4096
#define NC   256
#define NTHR 256

typedef float vfloat4 __attribute__((ext_vector_type(4)));

__global__ __launch_bounds__(NTHR) void cin2d_stats(
    const float* __restrict__ x,
    const int* __restrict__ style_id,
    const float* __restrict__ gamma,
    const float* __restrict__ beta,
    float2* __restrict__ ss)
{
    const int wave = threadIdx.x >> 6;
    const int lane = threadIdx.x & 63;
    const int inst = (blockIdx.x << 2) + wave;   // inst = b*NC + c
    const int b = inst >> 8;
    const int c = inst & (NC - 1);

    // 16 KiB instance, 64 lanes x 16 float4, fully coalesced 1 KiB segments.
    // CACHED loads on purpose: pass A streams all of x through L3 (128 MiB
    // fits in 256 MiB) so pass B's re-read is an L3 hit.
    const vfloat4* xp = (const vfloat4*)(x + (size_t)inst * HW) + lane;

    float s0 = 0.f, s1 = 0.f, s2 = 0.f, s3 = 0.f;
    float q0 = 0.f, q1 = 0.f, q2 = 0.f, q3 = 0.f;
#pragma unroll
    for (int i = 0; i < 16; ++i) {
        const vfloat4 d = xp[i * 64];
        s0 += d[0];  q0 = fmaf(d[0], d[0], q0);
        s1 += d[1];  q1 = fmaf(d[1], d[1], q1);
        s2 += d[2];  q2 = fmaf(d[2], d[2], q2);
        s3 += d[3];  q3 = fmaf(d[3], d[3], q3);
    }
    float s = (s0 + s1) + (s2 + s3);
    float q = (q0 + q1) + (q2 + q3);

    // Wave-wide butterfly; no LDS, no barriers, waves fully decoupled.
#pragma unroll
    for (int off = 1; off < 64; off <<= 1) {
        s += __shfl_xor(s, off, 64);
        q += __shfl_xor(q, off, 64);
    }

    if (lane == 0) {
        const float inv_n = 1.0f / (float)HW;
        const float mean = s * inv_n;
        float var = fmaf(-mean, mean, q * inv_n);   // biased variance
        var = var < 0.0f ? 0.0f : var;
        const float rstd = rsqrtf(var + 1e-5f);

        const int sid = style_id[b];
        const float g  = gamma[sid * NC + c];
        const float be = beta[sid * NC + c];

        const float scale = g * rstd;
        const float shift = fmaf(-mean, scale, be);
        ss[inst] = make_float2(scale, shift);
    }
}

__global__ __launch_bounds__(NTHR) void cin2d_apply(
    const float* __restrict__ x,
    const float2* __restrict__ ss,
    float* __restrict__ out)
{
    const int wave = threadIdx.x >> 6;
    const int lane = threadIdx.x & 63;
    const int inst = (blockIdx.x << 2) + wave;

    // Wave-uniform (scale, shift): one broadcast L2-hit load per wave.
    const float2 p = ss[inst];

    const vfloat4* xp = (const vfloat4*)(x   + (size_t)inst * HW) + lane;
    vfloat4*       op = (vfloat4*)      (out + (size_t)inst * HW) + lane;

    // Copy-shaped: each store depends only on its own load (L3-resident from
    // pass A). NT load = last touch; normal store = let L3 absorb writes.
#pragma unroll
    for (int i = 0; i < 16; ++i) {
        const vfloat4 d = __builtin_nontemporal_load(xp + i * 64);
        vfloat4 w;
#pragma unroll
        for (int j = 0; j < 4; ++j) w[j] = fmaf(d[j], p.x, p.y);
        op[i * 64] = w;
    }
}

extern "C" void kernel_launch(void* const* d_in, const int* in_sizes, int n_in,
                              void* d_out, int out_size, void* d_ws, size_t ws_size,
                              hipStream_t stream) {
    const float* x     = (const float*)d_in[0];
    const int*   sid   = (const int*)d_in[1];
    const float* gamma = (const float*)d_in[2];
    const float* beta  = (const float*)d_in[3];
    float* out = (float*)d_out;
    float2* ss = (float2*)d_ws;            // 8192 * 8 B = 64 KB

    const int B = 32, C = 256;
    dim3 grid((B * C) / 4), block(NTHR);   // 4 waves/block, 1 instance/wave

    hipLaunchKernelGGL(cin2d_stats, grid, block, 0, stream,
                       x, sid, gamma, beta, ss);
    hipLaunchKernelGGL(cin2d_apply, grid, block, 0, stream,
                       x, ss, out);
}

// Round 7
// 231.497 us; speedup vs baseline: 1.1433x; 1.1433x over previous
//
#include <hip/hip_runtime.h>

// Conditional InstanceNorm2d: x[B=32,C=256,H=64,W=64] fp32, style_id[B] int32,
// gamma/beta[S=16,C=256] fp32 -> out fp32.
//
// Dtype forensics (prior session): all tensors fp32, style_id int32, output
// fp32 (bf16 experiments -> NaN / packed-garbage mismatches).
//
// Session ledger (kernel us = total dur_us - ~157 us harness poison fills):
//   R0 block-lockstep 256thr (LDS reduce):   ~76 | total 233.0
//   R4 wave-per-instance (remat bug):        80.7 | 2.5 TB/s HBM, Occ 42%
//   R5 + asm-pin before accumulate:          ~78 | total 234.7
//   R6 persistent dbuf + NT STORES (64thr):  84.3 | Occ 17% (3 confounds)
//   R7 NT LOADS + cached stores:             ~72 | total 228.8  <- best
//   R8 two-pass (stats + copy-shaped apply): ~108 | total 264.7 REGRESSED
// R8's lesson: even pure-read and copy-shaped passes individually run at the
// same ~3.5 TB/s plateau -> L3 stream contention is NOT the mechanism.
//
// R9 model: wave-lifecycle gaps under a finite per-CU outstanding-read
// budget. Little's law on R4/R7 counters: ~3.7 TB/s at ~500 ns loaded
// latency implies only a few KiB of reads in flight per CU -- because each
// wave's pin-forced vmcnt(0) drain is followed by ~600+ cy of reduce (12
// serial shuffles) + store + exit with ZERO reads outstanding. Fast shapes
// (fill, m13 copy) never have such gaps.
// R9 = R7 + ONE variable: persistent waves, 4 contiguous instances each,
// register double-buffer -- next instance's 16 NT loads are issued BEFORE
// consuming the current tile, so counted vmcnt(16) waits keep a 16 KiB read
// burst in flight through reduce+store. Pin moved AFTER the accumulate
// (still blocks store-phase remat; no longer forces the early drain).
// NT loads + normal stores retained. 512 blocks x 4 waves = 2048 waves =
// 8/CU, all resident at t=0, zero block churn.
// Predict kernel ~55-62 us (total ~212-219), VGPR ~150-170, FETCH ~128 MiB.
// If flat: pipelining ruled out by two clean tests -> global_load_lds probe
// or roofline concession next.

#define HW   4096
#define NC   256
#define NPER 4             // instances per wave
#define NTHR 256           // 4 waves per block

typedef float vfloat4 __attribute__((ext_vector_type(4)));

__global__ __launch_bounds__(NTHR) void cin2d_kernel(
    const float* __restrict__ x,
    const int* __restrict__ style_id,
    const float* __restrict__ gamma,
    const float* __restrict__ beta,
    float* __restrict__ out)
{
    const int wave = threadIdx.x >> 6;
    const int lane = threadIdx.x & 63;
    // Each wave owns 4 CONTIGUOUS instances (64 KiB): block covers 16.
    const int inst0 = (blockIdx.x << 4) + (wave << 2);

    const vfloat4* xp = (const vfloat4*)(x   + (size_t)inst0 * HW) + lane;
    vfloat4*       op = (vfloat4*)      (out + (size_t)inst0 * HW) + lane;

    vfloat4 A[16], B[16];

    // Prologue: issue NT loads for instance 0 into A.
#pragma unroll
    for (int i = 0; i < 16; ++i)
        A[i] = __builtin_nontemporal_load(xp + i * 64);

    // One pipeline stage. CUR was loaded in a previous stage; NXT's loads are
    // issued here BEFORE CUR is consumed, so they stay in flight (counted
    // vmcnt) across CUR's reduce/store. All indices compile-time static.
    auto STEP = [&](vfloat4 (&CUR)[16], vfloat4 (&NXT)[16], int k,
                    bool prefetch) {
        if (prefetch) {
            const vfloat4* xn = xp + (size_t)(k + 1) * (HW / 4);
#pragma unroll
            for (int i = 0; i < 16; ++i)
                NXT[i] = __builtin_nontemporal_load(xn + i * 64);
        }

        // Style params for this instance (wave-uniform scalar loads; latency
        // overlaps the stats chain).
        const int inst = inst0 + k;
        const int b = inst >> 8;
        const int c = inst & (NC - 1);
        const int sid = style_id[b];
        const float g  = gamma[sid * NC + c];
        const float be = beta[sid * NC + c];

        // Accumulate FIRST, with compiler-managed counted vmcnt interleave
        // (no forced drain; the 16 newer prefetch loads stay outstanding).
        float s0 = 0.f, s1 = 0.f, s2 = 0.f, s3 = 0.f;
        float q0 = 0.f, q1 = 0.f, q2 = 0.f, q3 = 0.f;
#pragma unroll
        for (int i = 0; i < 16; ++i) {
            s0 += CUR[i][0];  q0 = fmaf(CUR[i][0], CUR[i][0], q0);
            s1 += CUR[i][1];  q1 = fmaf(CUR[i][1], CUR[i][1], q1);
            s2 += CUR[i][2];  q2 = fmaf(CUR[i][2], CUR[i][2], q2);
            s3 += CUR[i][3];  q3 = fmaf(CUR[i][3], CUR[i][3], q3);
        }
        float s = (s0 + s1) + (s2 + s3);
        float q = (q0 + q1) + (q2 + q3);

        // Pin AFTER the accumulate: values are in regs by now; the asm
        // redefinition forbids store-phase rematerialization (R4 bug) without
        // forcing an early vmcnt(0).
#pragma unroll
        for (int i = 0; i < 16; ++i) asm volatile("" : "+v"(CUR[i]));

        // Wave-wide butterfly: 6 steps, all lanes end with totals.
#pragma unroll
        for (int off = 1; off < 64; off <<= 1) {
            s += __shfl_xor(s, off, 64);
            q += __shfl_xor(q, off, 64);
        }

        const float inv_n = 1.0f / (float)HW;
        const float mean = s * inv_n;
        float var = fmaf(-mean, mean, q * inv_n);   // biased variance
        var = var < 0.0f ? 0.0f : var;
        const float rstd = rsqrtf(var + 1e-5f);

        const float scale = g * rstd;
        const float shift = fmaf(-mean, scale, be);

        // Normal cached stores (R6 showed NT stores regress).
        vfloat4* o = op + (size_t)k * (HW / 4);
#pragma unroll
        for (int i = 0; i < 16; ++i) {
            vfloat4 w;
#pragma unroll
            for (int j = 0; j < 4; ++j) w[j] = fmaf(CUR[i][j], scale, shift);
            o[i * 64] = w;
        }
    };

    STEP(A, B, 0, true);
    STEP(B, A, 1, true);
    STEP(A, B, 2, true);
    STEP(B, A, 3, false);
}

extern "C" void kernel_launch(void* const* d_in, const int* in_sizes, int n_in,
                              void* d_out, int out_size, void* d_ws, size_t ws_size,
                              hipStream_t stream) {
    const float* x     = (const float*)d_in[0];
    const int*   sid   = (const int*)d_in[1];
    const float* gamma = (const float*)d_in[2];
    const float* beta  = (const float*)d_in[3];
    float* out = (float*)d_out;

    const int B = 32, C = 256;
    dim3 grid((B * C) / (4 * NPER)), block(NTHR);  // 512 blocks, 2048 waves
    hipLaunchKernelGGL(cin2d_kernel, grid, block, 0, stream,
                       x, sid, gamma, beta, out);
}